// Round 5
// baseline (14683.516 us; speedup 1.0000x reference)
//
#include <hip/hip_runtime.h>

// GAT encoder, B=8, N=1024, D=768, H=4. adj int32; float tensors bf16 OR f32,
// runtime-detected (flag in ws), all reads/writes dispatch on the flag.
// Outputs: yy [B,N,D] then node_scores [B,N], concatenated in d_out (flag dtype).
//
// LEAN-WS ROUND (ws peak 6,824,192 B): per-(batch,head) pipeline.
//   ws: f1[1024]f32 @0, f2 @4096, flag @8192, Wh1 [1024,768]bf16 @8448,
//       Wh2 @1581312, att [1024,1024]bf16 @3154176, hout @5251328 (end 6824192)
// Per b: { per h: G1 Wh1=X[b]W[h]; F1; A1->att; G2 hout=elu(att@Wh1);
//          G3 Wh2 (+)= hout@Wo[h] }  F2; A2; G4 yy[b]=elu(att2@Wh2)+X[b]; then cls.

typedef unsigned short ushortT;

#define ALPHA 0.2f

__device__ __forceinline__ float b2f(ushortT u) {
  union { unsigned int i; float f; } c; c.i = ((unsigned int)u) << 16; return c.f;
}
__device__ __forceinline__ ushortT f2b(float f) {
  union { float f; unsigned int u; } c; c.f = f;
  unsigned int u = c.u;
  u += 0x7FFFu + ((u >> 16) & 1u);   // RNE
  return (ushortT)(u >> 16);
}

// ---- dtype detector: low 16-bit halves of f32 words are mantissa noise -------
__global__ void detect_dtype(const ushortT* __restrict__ X, int* __restrict__ flag) {
  __shared__ int s[256];
  int t = threadIdx.x, c = 0;
  for (int i = t; i < 16384; i += 256) {
    int e = (X[2 * i] >> 7) & 0xFF;
    if (e > 140 || e < 100) c++;     // genuine bf16 N(0,1): essentially never
  }
  s[t] = c; __syncthreads();
  for (int o = 128; o > 0; o >>= 1) { if (t < o) s[t] += s[t + o]; __syncthreads(); }
  if (t == 0) *flag = (s[0] > 1000) ? 1 : 0;   // 1 -> inputs are f32
}

// ---- tiled GEMM: C[1024(or less),768] tilegrid; C = A[.,K] @ B[K,768] --------
// aF32/bF32: 0 = bf16, 1 = f32, -1 = dispatch on *rflag.
// MODE 0: store bf16. MODE 1: elu, bf16. MODE 2: elu + residual(raw), store in
// flag dtype (this is the final output write). MODE 3: bf16 += accumulate.
template <int MODE>
__global__ __launch_bounds__(256) void sgemm(
    const void* __restrict__ Ab, const void* __restrict__ Bb,
    void* __restrict__ Cb, const void* __restrict__ Rb,
    int K, int lda, int ldb, int aF32, int bF32,
    long aOff, long bOff, long cOff, long rOff,
    int accum, const int* __restrict__ rflag) {
  __shared__ float As[64][17];
  __shared__ float Bs[16][65];
  int n0 = blockIdx.x * 64, m0 = blockIdx.y * 64;
  int tx = threadIdx.x & 15, ty = threadIdx.x >> 4, t = threadIdx.x;
  int flg = *rflag;
  int af32 = (aF32 < 0) ? flg : aF32;
  int bf32 = (bF32 < 0) ? flg : bF32;

  float acc[4][4];
#pragma unroll
  for (int r = 0; r < 4; r++)
#pragma unroll
    for (int c = 0; c < 4; c++) acc[r][c] = 0.f;

  const float* Af = (const float*)Ab; const ushortT* Au = (const ushortT*)Ab;
  const float* Bf = (const float*)Bb; const ushortT* Bu = (const ushortT*)Bb;

  for (int k0 = 0; k0 < K; k0 += 16) {
    __syncthreads();   // protect previous tile's LDS reads
    for (int i = t; i < 1024; i += 256) {       // A tile: 64 rows x 16 k
      int r = i >> 4, kk = i & 15;
      long gi = aOff + (long)(m0 + r) * lda + (k0 + kk);
      As[r][kk] = af32 ? Af[gi] : b2f(Au[gi]);
    }
    for (int i = t; i < 1024; i += 256) {       // B tile: 16 k x 64 cols
      int kk = i >> 6, c = i & 63;
      long gi = bOff + (long)(k0 + kk) * ldb + (n0 + c);
      Bs[kk][c] = bf32 ? Bf[gi] : b2f(Bu[gi]);
    }
    __syncthreads();
#pragma unroll
    for (int kk = 0; kk < 16; kk++) {
      float av[4], bv[4];
#pragma unroll
      for (int r = 0; r < 4; r++) av[r] = As[ty * 4 + r][kk];
#pragma unroll
      for (int c = 0; c < 4; c++) bv[c] = Bs[kk][tx * 4 + c];
#pragma unroll
      for (int r = 0; r < 4; r++)
#pragma unroll
        for (int c = 0; c < 4; c++) acc[r][c] += av[r] * bv[c];
    }
  }

  ushortT* Cu = (ushortT*)Cb; float* Cf = (float*)Cb;
#pragma unroll
  for (int r = 0; r < 4; r++) {
    int row = m0 + ty * 4 + r;
#pragma unroll
    for (int c = 0; c < 4; c++) {
      int col = n0 + tx * 4 + c;
      long ci = cOff + (long)row * 768 + col;
      float x = acc[r][c];
      if (MODE == 1 || MODE == 2) x = x > 0.f ? x : expm1f(x);
      if (MODE == 2) {
        long ri = rOff + (long)row * 768 + col;
        x += flg ? ((const float*)Rb)[ri] : b2f(((const ushortT*)Rb)[ri]);
      }
      if (MODE == 3 && accum) x += b2f(Cu[ci]);
      if (MODE == 2 && flg) Cf[ci] = x;
      else Cu[ci] = f2b(x);
    }
  }
}

// ---- f1/f2 dots: Wh [1024,768] bf16; avec raw (+elem offset); 4 nodes/block --
__global__ __launch_bounds__(256) void fdot_kernel(
    const ushortT* __restrict__ Wh, const void* __restrict__ avec, long aOff,
    float* __restrict__ f1, float* __restrict__ f2, const int* __restrict__ rflag) {
  int t = threadIdx.x, lane = t & 63, wid = t >> 6;
  int node = blockIdx.x * 4 + wid;
  int f32 = *rflag;
  const float* af = (const float*)avec;
  const ushortT* au = (const ushortT*)avec;
  const ushortT* row = Wh + (size_t)node * 768;
  float s1 = 0.f, s2 = 0.f;
  for (int f = lane; f < 768; f += 64) {
    float wv = b2f(row[f]);
    float a1 = f32 ? af[aOff + f] : b2f(au[aOff + f]);
    float a2 = f32 ? af[aOff + 768 + f] : b2f(au[aOff + 768 + f]);
    s1 += wv * a1;
    s2 += wv * a2;
  }
#pragma unroll
  for (int o = 32; o > 0; o >>= 1) {
    s1 += __shfl_down(s1, o);
    s2 += __shfl_down(s2, o);
  }
  if (lane == 0) { f1[node] = s1; f2[node] = s2; }
}

// ---- masked row softmax over 1024 cols; one block per row i ------------------
__global__ __launch_bounds__(256) void attn_kernel(
    const float* __restrict__ f1, const float* __restrict__ f2,
    const int* __restrict__ adj, ushortT* __restrict__ att) {
  __shared__ float sred[8];
  int i = blockIdx.x;
  const int* arow = adj + (size_t)i * 1024;
  float f1i = f1[i];
  ushortT* orow = att + (size_t)i * 1024;
  int t = threadIdx.x, lane = t & 63, wid = t >> 6;

  float e[4];
  int msk[4];
  float mx = -1e38f;
#pragma unroll
  for (int c = 0; c < 4; c++) {
    int j = t + c * 256;
    float ev = f1i + f2[j];
    ev = ev > 0.f ? ev : ALPHA * ev;
    e[c] = ev;
    msk[c] = arow[j] > 0;
    if (msk[c]) mx = fmaxf(mx, ev);
  }
#pragma unroll
  for (int o = 32; o > 0; o >>= 1) mx = fmaxf(mx, __shfl_down(mx, o));
  if (lane == 0) sred[wid] = mx;
  __syncthreads();
  float bmx = fmaxf(fmaxf(sred[0], sred[1]), fmaxf(sred[2], sred[3]));
  bool none = bmx < -1e37f;   // all-masked row -> reference softmax is uniform

  float p[4];
  float sum = 0.f;
#pragma unroll
  for (int c = 0; c < 4; c++) {
    p[c] = none ? 1.f : (msk[c] ? expf(e[c] - bmx) : 0.f);
    sum += p[c];
  }
#pragma unroll
  for (int o = 32; o > 0; o >>= 1) sum += __shfl_down(sum, o);
  if (lane == 0) sred[4 + wid] = sum;
  __syncthreads();
  float inv = 1.f / (sred[4] + sred[5] + sred[6] + sred[7]);
#pragma unroll
  for (int c = 0; c < 4; c++) orow[t + c * 256] = f2b(p[c] * inv);
}

// ---- classifier: scores[row] = sigmoid(yy[row]@w + b) * mask[row] ------------
__global__ __launch_bounds__(256) void cls_kernel(
    void* __restrict__ outbase, const void* __restrict__ w,
    const void* __restrict__ bc, const void* __restrict__ mask,
    const int* __restrict__ rflag) {
  int t = threadIdx.x, lane = t & 63, wv = t >> 6;
  long row = (long)blockIdx.x * 4 + wv;    // 0..8191
  int f32 = *rflag;
  const float* yf = (const float*)outbase; const ushortT* yu = (const ushortT*)outbase;
  const float* wf = (const float*)w;       const ushortT* wu = (const ushortT*)w;
  float s = 0.f;
  for (int d = lane; d < 768; d += 64) {
    float yv = f32 ? yf[row * 768 + d] : b2f(yu[row * 768 + d]);
    float wvv = f32 ? wf[d] : b2f(wu[d]);
    s += yv * wvv;
  }
#pragma unroll
  for (int o = 32; o > 0; o >>= 1) s += __shfl_down(s, o);
  if (lane == 0) {
    float bb = f32 ? ((const float*)bc)[0] : b2f(((const ushortT*)bc)[0]);
    float mk = f32 ? ((const float*)mask)[row] : b2f(((const ushortT*)mask)[row]);
    float sig = 1.f / (1.f + expf(-(s + bb)));
    long oi = 6291456L + row;
    if (f32) ((float*)outbase)[oi] = sig * mk;
    else ((ushortT*)outbase)[oi] = f2b(sig * mk);
  }
}

extern "C" void kernel_launch(void* const* d_in, const int* in_sizes, int n_in,
                              void* d_out, int out_size, void* d_ws, size_t ws_size,
                              hipStream_t stream) {
  (void)in_sizes; (void)n_in; (void)out_size; (void)ws_size;

  const void* X    = d_in[0];               // [8,1024,768]
  const int*  adj  = (const int*)d_in[1];   // [8,1024,1024]
  const void* maskN= d_in[2];               // [8,1024]
  const void* Wh   = d_in[3];               // [4,768,768]
  const void* aH   = d_in[4];               // [4,1536]
  const void* Wo   = d_in[5];               // [3072,768]
  const void* aO   = d_in[6];               // [1536]
  const void* wcls = d_in[7];               // [768]
  const void* bcls = d_in[8];               // [1]

  char* ws = (char*)d_ws;
  float*   f1     = (float*)(ws + 0);           // [1024]
  float*   f2     = (float*)(ws + 4096);        // [1024]
  int*     flag   = (int*)(ws + 8192);
  ushortT* Wh1buf = (ushortT*)(ws + 8448);      // [1024,768] bf16
  ushortT* Wh2buf = (ushortT*)(ws + 1581312);   // [1024,768] bf16
  ushortT* attbuf = (ushortT*)(ws + 3154176);   // [1024,1024] bf16
  ushortT* hout   = (ushortT*)(ws + 5251328);   // [1024,768] bf16; end 6,824,192

  detect_dtype<<<1, 256, 0, stream>>>((const ushortT*)X, flag);

  dim3 gg(12, 16);
  for (int b = 0; b < 8; b++) {
    long xOff = (long)b * 786432;
    for (int h = 0; h < 4; h++) {
      // G1: Wh1 = X[b] @ W_heads[h]   (A raw, B raw)
      sgemm<0><<<gg, 256, 0, stream>>>(
          X, Wh, Wh1buf, nullptr, 768, 768, 768, -1, -1,
          xOff, (long)h * 589824, 0L, 0L, 0, flag);
      // F1
      fdot_kernel<<<256, 256, 0, stream>>>(Wh1buf, aH, (long)h * 1536, f1, f2, flag);
      // A1
      attn_kernel<<<1024, 256, 0, stream>>>(f1, f2, adj + (size_t)b * 1048576, attbuf);
      // G2: hout = elu(att @ Wh1)
      sgemm<1><<<gg, 256, 0, stream>>>(
          attbuf, Wh1buf, hout, nullptr, 1024, 1024, 768, 0, 0,
          0L, 0L, 0L, 0L, 0, flag);
      // G3: Wh2 (+)= hout @ W_out[h*768: ,:]   (B raw)
      sgemm<3><<<gg, 256, 0, stream>>>(
          hout, Wo, Wh2buf, nullptr, 768, 768, 768, 0, -1,
          0L, (long)h * 589824, 0L, 0L, h > 0 ? 1 : 0, flag);
    }
    // F2 / A2 on layer-2 features
    fdot_kernel<<<256, 256, 0, stream>>>(Wh2buf, aO, 0L, f1, f2, flag);
    attn_kernel<<<1024, 256, 0, stream>>>(f1, f2, adj + (size_t)b * 1048576, attbuf);
    // G4: yy[b] = elu(att2 @ Wh2) + X[b]  -> d_out (flag dtype)
    sgemm<2><<<gg, 256, 0, stream>>>(
        attbuf, Wh2buf, d_out, X, 1024, 1024, 768, 0, 0,
        0L, 0L, xOff, xOff, 0, flag);
  }

  cls_kernel<<<2048, 256, 0, stream>>>(d_out, wcls, bcls, maskN, flag);
}